// Round 1
// 14153.391 us; speedup vs baseline: 1.1704x; 1.1704x over previous
//
#include <hip/hip_runtime.h>
#include <stdint.h>

// ---------------------------------------------------------------------------
// Bidirectional 2-layer LSTM.
//  Phase A (parallel): xg[scan][t][...] = x_t . W_ih^T + b   (bf16 MFMA GEMM)
//    -> stored in scan-consumption layout: per (t, mh, wave, lane) a 64B chunk
//       [uh(2)][gate(4)][r(4)] bf16, so the scan loads xg with 4x dwordx4.
//  Phase B (scan): 4 INDEPENDENT workgroups = (2 directions) x (2 batch-halves
//    of 16 rows). Each WG runs on one CU; no cross-WG sync at all.
//      - W_hh gates i,f,g resident in VGPRs (192 regs/wave, 8 waves = 384KB)
//      - W_hh o-gate staged in LDS (128KB), re-read per step
//      - h_{t-1} broadcast via LDS double buffer (16x528B rows, padded), one
//        __syncthreads per step. Critical path is intra-CU (~3000 cy/step)
//        instead of cross-XCD LLC round trips (~8900 cy/step before).
//    Per wave: 32 units x 4 gates, two uh-passes of 16 units (acc=16 regs)
//    to stay under the 256-VGPR cap at __launch_bounds__(512,2).
// MFMA 16x16x32 bf16:  A: (m=lane&15, k=quad*8+j)  B: (k=quad*8+j, n=lane&15)
//                      C/D: (row=quad*4+reg, col=lane&15)
// ---------------------------------------------------------------------------

#define Bn 32
#define Tn 2048
#define Hn 256

typedef short short8 __attribute__((ext_vector_type(8)));
typedef float f32x4 __attribute__((ext_vector_type(4)));
typedef unsigned int u32x4 __attribute__((ext_vector_type(4)));

__device__ inline unsigned short f2b(float f) {  // fp32 -> bf16 RNE
  union { float f; unsigned u; } v; v.f = f;
  unsigned r = v.u + 0x7fffu + ((v.u >> 16) & 1u);
  return (unsigned short)(r >> 16);
}
__device__ inline float asf(unsigned u) {
  union { unsigned u; float f; } v; v.u = u; return v.f;
}
__device__ inline float sigx(float x) {
  return __builtin_amdgcn_rcpf(1.f + __expf(-x));
}
__device__ inline float tanhx(float x) {
  return 2.f * __builtin_amdgcn_rcpf(1.f + __expf(-2.f * x)) - 1.f;
}

// ---------------- Phase A: xg = A . W^T + b  ------------------------------
// A: [B*T, K] (fp32 x if AF32 else bf16 h0out). Output xg bf16 in the scan
// layout described above. Wave owns a 32-gate stripe; stripe = g*8 + w'.
template <int K, bool AF32>
__global__ __launch_bounds__(256, 2) void xg_gemm(
    const void* __restrict__ Ain,
    const float* __restrict__ Wf, const float* __restrict__ bf_,
    const float* __restrict__ Wr, const float* __restrict__ br_,
    unsigned short* __restrict__ xg) {
  constexpr int KI = K / 32;
  const int bid = blockIdx.x;
  const int scan = bid & 1;
  const int sgrp = (bid >> 1) & 7;
  const int mchunk = bid >> 4;           // 0..255
  const int wave = threadIdx.x >> 6;
  const int lane = threadIdx.x & 63;
  const int l15 = lane & 15, quad = lane >> 4;
  const int stripe = sgrp * 4 + wave;    // 0..31 -> 32 gate-cols each
  const int gi0 = stripe * 32;
  const int wp = stripe & 7;             // scan-wave index this stripe feeds
  const int gg = stripe >> 3;            // gate index this stripe feeds

  const float* W = scan ? Wr : Wf;
  const float* bias = scan ? br_ : bf_;

  short8 bfr[KI][2];
  float bias2[2];
#pragma unroll
  for (int sub = 0; sub < 2; ++sub) {
    const int gi = gi0 + sub * 16 + l15;
    bias2[sub] = bias[gi];
#pragma unroll
    for (int ki = 0; ki < KI; ++ki) {
      const float* src = W + (size_t)gi * K + ki * 32 + quad * 8;
      short8 v;
#pragma unroll
      for (int j = 0; j < 8; ++j) v[j] = (short)f2b(src[j]);
      bfr[ki][sub] = v;
    }
  }

  const size_t scanoff = (size_t)scan << 26;  // elements (128MB per scan)
#pragma unroll 1
  for (int mt0 = 0; mt0 < 16; ++mt0) {
    const int mt = mchunk * 16 + mt0;
    const size_t row = (size_t)mt * 16 + l15;
    f32x4 acc[2];
#pragma unroll
    for (int sub = 0; sub < 2; ++sub) {
      f32x4 bi = {bias2[sub], bias2[sub], bias2[sub], bias2[sub]};
      acc[sub] = bi;
    }
#pragma unroll
    for (int ki = 0; ki < KI; ++ki) {
      short8 af;
      if constexpr (AF32) {
        const float* ap = (const float*)Ain + row * K + ki * 32 + quad * 8;
        f32x4 a0 = *(const f32x4*)ap;
        f32x4 a1 = *(const f32x4*)(ap + 4);
#pragma unroll
        for (int j = 0; j < 4; ++j) { af[j] = (short)f2b(a0[j]); af[4 + j] = (short)f2b(a1[j]); }
      } else {
        const unsigned short* ap = (const unsigned short*)Ain + row * K + ki * 32 + quad * 8;
        af = *(const short8*)ap;
      }
#pragma unroll
      for (int sub = 0; sub < 2; ++sub)
        acc[sub] = __builtin_amdgcn_mfma_f32_16x16x32_bf16(af, bfr[ki][sub], acc[sub], 0, 0, 0);
    }
    // store in scan layout: elem = scanoff + ((t*2+mh)*8+wp)*2048
    //                        + (quad'*16 + l15)*32 + uh*16 + g*4 + r'
    //   with m=batch: mh=m>>4, quad'=(m>>2)&3, r'=m&3 ; uh=sub.
#pragma unroll
    for (int sub = 0; sub < 2; ++sub) {
#pragma unroll
      for (int r = 0; r < 4; ++r) {
        const int orow = mt * 16 + quad * 4 + r;
        const int m = orow >> 11, t = orow & 2047;
        size_t idx = scanoff
          + ((((size_t)t * 2 + (m >> 4)) * 8 + wp) << 11)
          + ((size_t)((((m >> 2) & 3) << 4) + l15) << 5)
          + (sub << 4) + (gg << 2) + (m & 3);
        xg[idx] = f2b(acc[sub][r]);
      }
    }
  }
}

// ---------------- Phase B: recurrent scan (independent per block) ----------
// grid = 4: block = scan*1 + mh*2?  -> scan = bid&1, mh = bid>>1.
// 512 threads = 8 waves, one CU, 1 WG/CU (LDS 145KB + 256 VGPR).
template <bool LAYER1>
__global__ __launch_bounds__(512, 2) void lstm_scan(
    const unsigned short* __restrict__ xg,   // scan layout, bf16
    const float* __restrict__ Whh_f, const float* __restrict__ Whh_r,
    unsigned short* __restrict__ h0out,      // [B][T][512] bf16 (layer0)
    float* __restrict__ dout) {              // [B][T][512] f32  (layer1)
  // LDS: [0,131072)           W_hh o-gate frags: ((w*2+uh)*8+ki)*1024 + lane*16
  //      [131072, 147968)     h double buffer: p*8448 + row*528 + unit*2
  __shared__ __align__(16) char smem[131072 + 2 * 8448];

  const int bid = blockIdx.x;
  const int scan = bid & 1;
  const int mh = bid >> 1;                 // batch half (16 rows)
  const int wave = threadIdx.x >> 6;
  const int lane = threadIdx.x & 63;
  const int l15 = lane & 15, quad = lane >> 4;

  const float* Whh = scan ? Whh_r : Whh_f;

  // ---- resident W_hh fragments: gates 0..2, [uh][g][ki] = 192 VGPR ----
  short8 wres[2][3][8];
#pragma unroll
  for (int uh = 0; uh < 2; ++uh)
#pragma unroll
    for (int g = 0; g < 3; ++g)
#pragma unroll
      for (int ki = 0; ki < 8; ++ki) {
        const int col = g * 256 + wave * 32 + uh * 16 + l15;
        const float* src = Whh + ((size_t)col << 8) + ki * 32 + quad * 8;
        f32x4 a0 = *(const f32x4*)src;
        f32x4 a1 = *(const f32x4*)(src + 4);
        short8 v;
#pragma unroll
        for (int j = 0; j < 4; ++j) { v[j] = (short)f2b(a0[j]); v[4 + j] = (short)f2b(a1[j]); }
        wres[uh][g][ki] = v;
      }
  // ---- o-gate (g=3) fragments -> LDS ----
#pragma unroll
  for (int uh = 0; uh < 2; ++uh)
#pragma unroll
    for (int ki = 0; ki < 8; ++ki) {
      const int col = 768 + wave * 32 + uh * 16 + l15;
      const float* src = Whh + ((size_t)col << 8) + ki * 32 + quad * 8;
      f32x4 a0 = *(const f32x4*)src;
      f32x4 a1 = *(const f32x4*)(src + 4);
      short8 v;
#pragma unroll
      for (int j = 0; j < 4; ++j) { v[j] = (short)f2b(a0[j]); v[4 + j] = (short)f2b(a1[j]); }
      *(short8*)(smem + ((((wave << 1) + uh) << 3) + ki) * 1024 + lane * 16) = v;
    }

  // ---- xg prefetch (t0) ----
  const size_t scanoff = (size_t)scan << 26;  // elements
  const int tstep = scan ? -1 : 1;
  const int t0 = scan ? (Tn - 1) : 0;
  const size_t lane_off = (size_t)lane * 32;  // elements within (t,mh,w) chunk
  u32x4 xr[2][2];
  {
    const unsigned short* xb =
        xg + scanoff + ((((size_t)t0 * 2 + mh) * 8 + wave) << 11) + lane_off;
    xr[0][0] = *(const u32x4*)(xb + 0);
    xr[0][1] = *(const u32x4*)(xb + 8);
    xr[1][0] = *(const u32x4*)(xb + 16);
    xr[1][1] = *(const u32x4*)(xb + 24);
  }

  char* hbuf = smem + 131072;
  float c_st[2][4] = {{0.f, 0.f, 0.f, 0.f}, {0.f, 0.f, 0.f, 0.f}};

  __syncthreads();  // W-LDS ready

#pragma unroll 1
  for (int s = 0; s < Tn; ++s) {
    const int t = scan ? (Tn - 1 - s) : s;
    const int tn = (s < Tn - 1) ? (t + tstep) : t;  // next-step prefetch (clamped)
    const unsigned short* xbn =
        xg + scanoff + ((((size_t)tn * 2 + mh) * 8 + wave) << 11) + lane_off;
    const int p_r = (s - 1) & 1, p_w = s & 1;

#pragma unroll
    for (int uh = 0; uh < 2; ++uh) {
      // [A] acc init from xg (bf16 pairs -> f32)
      f32x4 acc[4];
#pragma unroll
      for (int g = 0; g < 4; ++g) {
        unsigned lo = xr[uh][g >> 1][2 * (g & 1)];
        unsigned hi = xr[uh][g >> 1][2 * (g & 1) + 1];
        acc[g][0] = asf(lo << 16); acc[g][1] = asf(lo & 0xffff0000u);
        acc[g][2] = asf(hi << 16); acc[g][3] = asf(hi & 0xffff0000u);
      }
      if (uh == 1) {  // uh0 regs free since pass0 [A]; refill early for next t
        xr[0][0] = *(const u32x4*)(xbn + 0);
        xr[0][1] = *(const u32x4*)(xbn + 8);
      }

      // [B] h_{t-1} @ W_hh^T
      if (s > 0) {
        const char* hr = hbuf + p_r * 8448 + l15 * 528 + quad * 16;
        const char* wl0 = smem + (((wave << 1) + uh) << 13) + lane * 16;
#pragma unroll
        for (int ki = 0; ki < 8; ++ki) {
          short8 a = *(const short8*)(hr + (ki << 6));
          short8 wl = *(const short8*)(wl0 + (ki << 10));
          acc[0] = __builtin_amdgcn_mfma_f32_16x16x32_bf16(a, wres[uh][0][ki], acc[0], 0, 0, 0);
          acc[1] = __builtin_amdgcn_mfma_f32_16x16x32_bf16(a, wres[uh][1][ki], acc[1], 0, 0, 0);
          acc[2] = __builtin_amdgcn_mfma_f32_16x16x32_bf16(a, wres[uh][2][ki], acc[2], 0, 0, 0);
          acc[3] = __builtin_amdgcn_mfma_f32_16x16x32_bf16(a, wl,              acc[3], 0, 0, 0);
        }
      }

      // [D] gates + state ; [E] h -> LDS (packed pairs) + output store
      const int ubase = wave * 32 + uh * 16 + l15;
#pragma unroll
      for (int r = 0; r < 4; ++r) {
        float ig = sigx(acc[0][r]), fg = sigx(acc[1][r]);
        float gc = tanhx(acc[2][r]), og = sigx(acc[3][r]);
        float cv = fg * c_st[uh][r] + ig * gc;
        c_st[uh][r] = cv;
        float hv = og * tanhx(cv);
        unsigned short h16 = f2b(hv);
        int pk = __shfl_xor((int)h16, 1);
        const int row = quad * 4 + r;
        if (!(lane & 1)) {
          unsigned pv = (unsigned)h16 | ((unsigned)pk << 16);
          *(unsigned*)(hbuf + p_w * 8448 + row * 528 + ubase * 2) = pv;
        }
        const int b = mh * 16 + row;
        if constexpr (!LAYER1) {
          h0out[(((size_t)b * Tn + t) << 9) + scan * Hn + ubase] = h16;
        } else {
          dout[(((size_t)b * Tn + t) << 9) + scan * Hn + ubase] = hv;
        }
      }

      if (uh == 1) {  // uh1 regs free since this pass's [A]; refill for next t
        xr[1][0] = *(const u32x4*)(xbn + 16);
        xr[1][1] = *(const u32x4*)(xbn + 24);
      }
    }

    __syncthreads();  // h[p_w] published; previous buffer reads all complete
  }
}

extern "C" void kernel_launch(void* const* d_in, const int* in_sizes, int n_in,
                              void* d_out, int out_size, void* d_ws, size_t ws_size,
                              hipStream_t stream) {
  (void)in_sizes; (void)n_in; (void)out_size; (void)ws_size;
  const float* x      = (const float*)d_in[0];
  const float* Wih_f0 = (const float*)d_in[1];
  const float* Whh_f0 = (const float*)d_in[2];
  const float* b_f0   = (const float*)d_in[3];
  const float* Wih_r0 = (const float*)d_in[4];
  const float* Whh_r0 = (const float*)d_in[5];
  const float* b_r0   = (const float*)d_in[6];
  const float* Wih_f1 = (const float*)d_in[7];
  const float* Whh_f1 = (const float*)d_in[8];
  const float* b_f1   = (const float*)d_in[9];
  const float* Wih_r1 = (const float*)d_in[10];
  const float* Whh_r1 = (const float*)d_in[11];
  const float* b_r1   = (const float*)d_in[12];

  char* ws = (char*)d_ws;
  unsigned short* xgbuf = (unsigned short*)ws;                 // 268,435,456 B
  size_t off = (size_t)2 * Tn * Bn * 1024 * sizeof(unsigned short);
  unsigned short* h0out = (unsigned short*)(ws + off);         // 67,108,864 B

  dim3 blkA(256), blkB(512);
  // layer 0
  xg_gemm<256, true><<<dim3(4096), blkA, 0, stream>>>(
      (const void*)x, Wih_f0, b_f0, Wih_r0, b_r0, xgbuf);
  lstm_scan<false><<<dim3(4), blkB, 0, stream>>>(
      xgbuf, Whh_f0, Whh_r0, h0out, (float*)nullptr);
  // layer 1
  xg_gemm<512, false><<<dim3(4096), blkA, 0, stream>>>(
      (const void*)h0out, Wih_f1, b_f1, Wih_r1, b_r1, xgbuf);
  lstm_scan<true><<<dim3(4), blkB, 0, stream>>>(
      xgbuf, Whh_f1, Whh_r1, (unsigned short*)nullptr, (float*)d_out);
}